// Round 2
// baseline (672.713 us; speedup 1.0000x reference)
//
#include <hip/hip_runtime.h>
#include <stdint.h>

typedef unsigned short u16;
using bf16x8 = __attribute__((ext_vector_type(8))) __bf16;
using f32x4  = __attribute__((ext_vector_type(4))) float;
using u16x8  = __attribute__((ext_vector_type(8))) u16;
using u16x4  = __attribute__((ext_vector_type(4))) u16;
using i32x4  = __attribute__((ext_vector_type(4))) int;

#define BB 2
#define TT 2048
#define SQ 2048
#define DM 1024
#define NH 16
#define HD 64
#define LOG2E 1.44269504088896340736f

__device__ __forceinline__ float bf2f(u16 u) {
  uint32_t x = ((uint32_t)u) << 16;
  return __builtin_bit_cast(float, x);
}
__device__ __forceinline__ u16 f2bf(float f) {
  uint32_t x = __builtin_bit_cast(uint32_t, f);
  x += 0x7fffu + ((x >> 16) & 1u);
  return (u16)(x >> 16);
}
__device__ __forceinline__ int cvt_pk_bf16(float lo, float hi) {
  int r;
  asm("v_cvt_pk_bf16_f32 %0, %1, %2" : "=v"(r) : "v"(lo), "v"(hi));
  return r;
}

typedef __attribute__((address_space(1))) void gvoid;
typedef __attribute__((address_space(3))) void lvoid;
__device__ __forceinline__ void g2l16(const void* g, void* l) {
  // async global->LDS, 16B per lane, LDS dest = base + lane*16
  __builtin_amdgcn_global_load_lds((gvoid*)g, (lvoid*)l, 16, 0, 0);
}

// ---------------- fp32 -> bf16 convert (all 5 tensors, one launch) ----------
__global__ __launch_bounds__(256) void convert_all(
    const float* __restrict__ q, const float* __restrict__ k,
    const float* __restrict__ v, const float* __restrict__ wq,
    const float* __restrict__ wo, u16* __restrict__ qc, u16* __restrict__ kc,
    u16* __restrict__ vc, u16* __restrict__ wqc, u16* __restrict__ woc) {
  const float* src;
  u16* dst;
  int n8;
  switch (blockIdx.y) {
    case 0:  src = q;  dst = qc;  n8 = 4096 * 1024 / 8; break;
    case 1:  src = k;  dst = kc;  n8 = 4096 * 1024 / 8; break;
    case 2:  src = v;  dst = vc;  n8 = 4096 * 1024 / 8; break;
    case 3:  src = wq; dst = wqc; n8 = 1024 * 1024 / 8; break;
    default: src = wo; dst = woc; n8 = 1024 * 1024 / 8; break;
  }
  int i = blockIdx.x * 256 + threadIdx.x;
  if (i >= n8) return;
  f32x4 a = ((const f32x4*)src)[(size_t)i * 2];
  f32x4 b = ((const f32x4*)src)[(size_t)i * 2 + 1];
  u16x8 o;
#pragma unroll
  for (int j = 0; j < 4; ++j) { o[j] = f2bf(a[j]); o[4 + j] = f2bf(b[j]); }
  ((u16x8*)dst)[i] = o;
}

// ---------------- GEMM-BT: C[M,1024] = A[M,1024] @ W[1024,1024]^T (bf16) -----
// 128x128 tile, BK=64, fragment-blocked LDS (1KB frags in exact lane order).
// norm_mode: 0 = l2norm rows per 64-col head + logit-scale*log2e (q)
//            1 = l2norm rows per 64-col head (k)
//            2 = plain (v)
template <typename OutT>
__device__ __forceinline__ void gemm_body(const u16* __restrict__ A,
                                          const u16* __restrict__ W,
                                          OutT* __restrict__ C,
                                          const float* __restrict__ ls,
                                          int norm_mode) {
  const int n0 = blockIdx.x * 128;
  const int m0 = blockIdx.y * 128;
  const int tid = threadIdx.x;
  const int w = tid >> 6, lane = tid & 63;
  const int l15 = lane & 15, lg = lane >> 4;
  const int wr = w >> 1, wc = w & 1;

  __shared__ u16 ldsA[16 * 512];
  __shared__ u16 ldsB[16 * 512];

  f32x4 acc[4][4];
#pragma unroll
  for (int i = 0; i < 4; ++i)
#pragma unroll
    for (int j = 0; j < 4; ++j) acc[i][j] = (f32x4){0.f, 0.f, 0.f, 0.f};

  for (int kt = 0; kt < 1024; kt += 64) {
#pragma unroll
    for (int u = 0; u < 4; ++u) {
      int f = w * 4 + u;           // frag id 0..15
      int mt = f >> 1, ks = f & 1; // frag(mt,ks): lane -> [mt*16+l15][ks*32+lg*8]
      g2l16(A + (size_t)(m0 + mt * 16 + l15) * 1024 + kt + ks * 32 + lg * 8,
            &ldsA[f * 512]);
      g2l16(W + (size_t)(n0 + mt * 16 + l15) * 1024 + kt + ks * 32 + lg * 8,
            &ldsB[f * 512]);
    }
    __syncthreads();
#pragma unroll
    for (int ks = 0; ks < 2; ++ks) {
      bf16x8 a[4], b[4];
#pragma unroll
      for (int i = 0; i < 4; ++i)
        a[i] = *(const bf16x8*)&ldsA[((wr * 4 + i) * 2 + ks) * 512 + lane * 8];
#pragma unroll
      for (int j = 0; j < 4; ++j)
        b[j] = *(const bf16x8*)&ldsB[((wc * 4 + j) * 2 + ks) * 512 + lane * 8];
#pragma unroll
      for (int i = 0; i < 4; ++i)
#pragma unroll
        for (int j = 0; j < 4; ++j)
          acc[i][j] = __builtin_amdgcn_mfma_f32_16x16x32_bf16(a[i], b[j],
                                                              acc[i][j], 0, 0, 0);
    }
    __syncthreads();
  }

  // fused per-(row,head) l2norm (+ clamped logit scale for q). Each wave owns
  // one head's 64 cols: col = (wc*4+j)*16+l15 -> head = n0/64 + wc.
  if (norm_mode < 2) {
    float sc = 1.0f;
    if (norm_mode == 0)
      sc = __expf(fminf(ls[(n0 >> 6) + wc], 4.60517019f)) * LOG2E;  // exp2 fold
#pragma unroll
    for (int i = 0; i < 4; ++i)
#pragma unroll
      for (int r = 0; r < 4; ++r) {
        float ss = 0.f;
#pragma unroll
        for (int j = 0; j < 4; ++j) ss += acc[i][j][r] * acc[i][j][r];
#pragma unroll
        for (int d = 1; d < 16; d <<= 1) ss += __shfl_xor(ss, d, 64);
        float f = sc / fmaxf(sqrtf(ss), 1e-12f);
#pragma unroll
        for (int j = 0; j < 4; ++j) acc[i][j][r] *= f;
      }
  }

#pragma unroll
  for (int i = 0; i < 4; ++i) {
    int row0 = m0 + (wr * 4 + i) * 16 + lg * 4;
#pragma unroll
    for (int j = 0; j < 4; ++j) {
      int col = n0 + (wc * 4 + j) * 16 + l15;
#pragma unroll
      for (int r = 0; r < 4; ++r) {
        if constexpr (sizeof(OutT) == 2)
          C[(size_t)(row0 + r) * 1024 + col] = f2bf(acc[i][j][r]);
        else
          C[(size_t)(row0 + r) * 1024 + col] = acc[i][j][r];
      }
    }
  }
}

__global__ __launch_bounds__(256, 2) void gemm_qkv(
    const u16* __restrict__ q, const u16* __restrict__ k,
    const u16* __restrict__ v, const u16* __restrict__ W,
    const float* __restrict__ ls,
    u16* __restrict__ qp, u16* __restrict__ kp, u16* __restrict__ vp) {
  const u16* A;
  u16* C;
  if (blockIdx.z == 0) { A = q; C = qp; }
  else if (blockIdx.z == 1) { A = k; C = kp; }
  else { A = v; C = vp; }
  gemm_body<u16>(A, W, C, ls, blockIdx.z);
}

__global__ __launch_bounds__(256, 2) void gemm_out(const u16* __restrict__ A,
                                                   const u16* __restrict__ W,
                                                   float* __restrict__ C) {
  gemm_body<float>(A, W, C, nullptr, 2);
}

// -------- vt[b][h][d][s] = vp[(b*S+s)*1024 + h*64 + d] --------
__global__ __launch_bounds__(256) void transpose_v(const u16* __restrict__ vp,
                                                   u16* __restrict__ vt) {
  int st = blockIdx.x;           // s-tile (64)
  int bh = blockIdx.y;           // b*16+h
  __shared__ u16 lds[64][72];
  int tid = threadIdx.x;
  int s = tid >> 2, c0 = (tid & 3) * 16;
  int b = bh >> 4, h = bh & 15;
  const u16* src = vp + (size_t)(b * SQ + st * 64 + s) * 1024 + h * 64 + c0;
  u16x8 r0 = *(const u16x8*)src;
  u16x8 r1 = *(const u16x8*)(src + 8);
#pragma unroll
  for (int j = 0; j < 8; ++j) { lds[s][c0 + j] = r0[j]; lds[s][c0 + 8 + j] = r1[j]; }
  __syncthreads();
  int d = tid >> 2, sc = (tid & 3) * 16;
  u16x8 o0, o1;
#pragma unroll
  for (int j = 0; j < 8; ++j) { o0[j] = lds[sc + j][d]; o1[j] = lds[sc + 8 + j][d]; }
  u16* dst = vt + (size_t)(bh * 64 + d) * SQ + st * 64 + sc;
  *(u16x8*)dst = o0;
  *((u16x8*)(dst + 8)) = o1;
}

// -------- bt[h][t][s] (bf16, pre-scaled by log2e) = bias[t][s][h] (fp32) -----
// v3: unit-stride global reads (lane i reads 16B at base + i*16), LDS transpose.
__global__ __launch_bounds__(256) void transpose_bias(const float* __restrict__ bias,
                                                      u16* __restrict__ bt) {
  int t = blockIdx.y;
  int s0 = blockIdx.x * 512;
  __shared__ u16 lds[16][520];
  int tid = threadIdx.x;
  const float* src = bias + ((size_t)t * SQ + s0) * 16;  // block base, 32 KB
  int h0 = (tid & 3) * 4;
  int sr = tid >> 2;  // 0..63
#pragma unroll
  for (int p = 0; p < 8; ++p) {
    // flat float index = p*1024 + tid*4 + e -> s = p*64 + (tid>>2), h = (tid&3)*4+e
    f32x4 r = *(const f32x4*)(src + p * 1024 + tid * 4);
#pragma unroll
    for (int e = 0; e < 4; ++e)
      lds[h0 + e][p * 64 + sr] = f2bf(r[e] * LOG2E);
  }
  __syncthreads();
  int h = tid >> 4, sc = (tid & 15) * 32;
  u16* dst = bt + ((size_t)h * TT + t) * SQ + s0 + sc;
#pragma unroll
  for (int j = 0; j < 4; ++j) {
    u16x8 o;
#pragma unroll
    for (int e = 0; e < 8; ++e) o[e] = lds[h][sc + j * 8 + e];
    *((u16x8*)(dst + j * 8)) = o;
  }
}

// -------- flash attention, BK=128, fixed-max softmax (scores bounded) --------
// v3: both batches merged into one 512-thread block (waves 0-3: b=0, 4-7: b=1)
// so the bias tile is read once per (h,qt) — the b=1 waves' bias loads hit L1.
// Swapped QK^T (P lane-local), in-register P via cvt_pk + permlane swaps,
// double-buffered K/V staging with counted vmcnt, exp2 with log2e folded
// upstream into qn and bt. LDS 128 KB -> 1 block/CU (8 waves, same as before).
__global__ __launch_bounds__(512, 2) void flash_attn(
    const u16* __restrict__ qn, const u16* __restrict__ kn,
    const u16* __restrict__ vt, const u16* __restrict__ bt,
    u16* __restrict__ av) {
  const int h = blockIdx.x, qt = blockIdx.y;
  const int tid = threadIdx.x, lane = tid & 63;
  const int wAll = tid >> 6;
  const int b = wAll >> 2, w = wAll & 3;
  const int l15 = lane & 15, lg = lane >> 4;

  __shared__ u16 ldsK[2][2][16 * 512];  // [buf][b][frag] 64 KB
  __shared__ u16 ldsV[2][2][16 * 512];  // 64 KB

  const int t0 = qt * 64 + w * 16;

  bf16x8 qf[2];
  {
    const u16* qb = qn + (size_t)(b * TT + t0 + l15) * 1024 + h * 64 + lg * 8;
    qf[0] = *(const bf16x8*)qb;
    qf[1] = *(const bf16x8*)(qb + 32);
  }

  f32x4 o[4];
#pragma unroll
  for (int n = 0; n < 4; ++n) o[n] = (f32x4){0.f, 0.f, 0.f, 0.f};
  float li = 0.f;

  const u16* kb = kn + (size_t)(b * SQ) * 1024 + h * 64;
  const u16* vb = vt + (size_t)((b * NH + h) * 64) * SQ;
  // S^T layout: lane needs bias[t = t0+l15][s = st + nt*16 + lg*4 + r]
  // (identical addresses for the b=0 and b=1 wave quartets -> L1 reuse)
  const u16* bbl = bt + ((size_t)h * TT + t0 + l15) * SQ + lg * 4;

#define STAGE(bufi, stg)                                                       \
  {                                                                            \
    _Pragma("unroll") for (int u_ = 0; u_ < 4; ++u_) {                         \
      int f_ = w * 4 + u_;                                                     \
      int nt_ = f_ >> 1, ks_ = f_ & 1;                                         \
      g2l16(kb + (size_t)((stg) + nt_ * 16 + l15) * 1024 + ks_ * 32 + lg * 8,  \
            &ldsK[bufi][b][f_ * 512]);                                         \
      int j_ = f_ >> 2, k2_ = f_ & 3;                                          \
      g2l16(vb + (size_t)(j_ * 16 + l15) * SQ + (stg) + k2_ * 32 + lg * 8,     \
            &ldsV[bufi][b][f_ * 512]);                                         \
    }                                                                          \
  }

  STAGE(0, 0);  // prologue: 8 staging loads in flight per wave

  for (int it = 0; it < 16; ++it) {
    const int cur = it & 1;
    const int st = it * 128;

    // bias tile: 8 x dwordx2, issued BEFORE next-stage so the counted waits
    // below are exact (outstanding = cur8 | bias8 | next8).
    u16x4 bv[8];
#pragma unroll
    for (int nt = 0; nt < 8; ++nt)
      bv[nt] = *(const u16x4*)(bbl + st + nt * 16);
    asm volatile("" ::: "memory");  // pin bias loads before staging issue

    if (it < 15) {
      STAGE(cur ^ 1, st + 128);
      // retire cur's 8 staging loads; keep bias(8)+next(8) in flight
      asm volatile("s_waitcnt vmcnt(16)" ::: "memory");
    } else {
      // no next-stage: retire cur's 8, keep bias(8)
      asm volatile("s_waitcnt vmcnt(8)" ::: "memory");
    }
    __builtin_amdgcn_s_barrier();

    // S^T = Kn @ Qn^T: A = K-frag (rows = s), B = Q-frag (cols = t).
    // sacc[nt][r] = S[t = l15][s = st + nt*16 + lg*4 + r]
    f32x4 sacc[8];
#pragma unroll
    for (int nt = 0; nt < 8; ++nt) {
      sacc[nt] = (f32x4){0.f, 0.f, 0.f, 0.f};
#pragma unroll
      for (int ks = 0; ks < 2; ++ks)
        sacc[nt] = __builtin_amdgcn_mfma_f32_16x16x32_bf16(
            *(const bf16x8*)&ldsK[cur][b][(nt * 2 + ks) * 512 + lane * 8],
            qf[ks], sacc[nt], 0, 0, 0);
    }

    // p = exp2(s + bias); lane-local sum; pack pairs to bf16
    int pk[8][2];
#pragma unroll
    for (int nt = 0; nt < 8; ++nt) {
      float p0 = __builtin_amdgcn_exp2f(sacc[nt][0] + bf2f(bv[nt][0]));
      float p1 = __builtin_amdgcn_exp2f(sacc[nt][1] + bf2f(bv[nt][1]));
      float p2 = __builtin_amdgcn_exp2f(sacc[nt][2] + bf2f(bv[nt][2]));
      float p3 = __builtin_amdgcn_exp2f(sacc[nt][3] + bf2f(bv[nt][3]));
      li += (p0 + p1) + (p2 + p3);
      pk[nt][0] = cvt_pk_bf16(p0, p1);
      pk[nt][1] = cvt_pk_bf16(p2, p3);
    }

    // O += P @ V. Build P A-fragments in-register:
    //   (u,v) = permlane32_swap(A,B)   -> u=[A0,A1,B0,B1], v=[A2,A3,B2,B3]
    //   (u',v') = permlane16_swap(u,v) -> u'=[A0,A2,B0,B2], v'=[A1,A3,B1,B3]
#pragma unroll
    for (int ks2 = 0; ks2 < 4; ++ks2) {
      auto a0 = __builtin_amdgcn_permlane32_swap(pk[2 * ks2][0],
                                                 pk[2 * ks2 + 1][0], false, false);
      auto w0 = __builtin_amdgcn_permlane16_swap(a0[0], a0[1], false, false);
      auto a1 = __builtin_amdgcn_permlane32_swap(pk[2 * ks2][1],
                                                 pk[2 * ks2 + 1][1], false, false);
      auto w1 = __builtin_amdgcn_permlane16_swap(a1[0], a1[1], false, false);
      i32x4 pw = (i32x4){(int)w0[0], (int)w1[0], (int)w0[1], (int)w1[1]};
      bf16x8 pf = __builtin_bit_cast(bf16x8, pw);
#pragma unroll
      for (int j = 0; j < 4; ++j)
        o[j] = __builtin_amdgcn_mfma_f32_16x16x32_bf16(
            pf, *(const bf16x8*)&ldsV[cur][b][(j * 4 + ks2) * 512 + lane * 8],
            o[j], 0, 0, 0);
    }
    // protect buf[cur] from next iteration's staging overwrite
    if (it < 15) __builtin_amdgcn_s_barrier();
  }
#undef STAGE

  // li holds partial sum for t = l15 over this lane-group's s subset
  li += __shfl_xor(li, 16, 64);
  li += __shfl_xor(li, 32, 64);
  float inv[4];
#pragma unroll
  for (int r = 0; r < 4; ++r) inv[r] = 1.0f / __shfl(li, lg * 4 + r, 64);

#pragma unroll
  for (int j = 0; j < 4; ++j)
#pragma unroll
    for (int r = 0; r < 4; ++r) {
      size_t row = (size_t)(b * TT + t0 + lg * 4 + r);
      av[row * 1024 + h * 64 + j * 16 + l15] = f2bf(o[j][r] * inv[r]);
    }
}

extern "C" void kernel_launch(void* const* d_in, const int* in_sizes, int n_in,
                              void* d_out, int out_size, void* d_ws, size_t ws_size,
                              hipStream_t stream) {
  const float* q    = (const float*)d_in[0];
  const float* k    = (const float*)d_in[1];
  const float* v    = (const float*)d_in[2];
  const float* bias = (const float*)d_in[3];
  const float* Wqkv = (const float*)d_in[4];
  const float* Wout = (const float*)d_in[5];
  const float* ls   = (const float*)d_in[6];
  float* out = (float*)d_out;

  char* ws = (char*)d_ws;
  u16* qc = (u16*)(ws);                       // 8 MiB bf16 [4096,1024]
  u16* kc = (u16*)(ws + (size_t)(8  << 20));  // 8 MiB
  u16* vc = (u16*)(ws + (size_t)(16 << 20));  // 8 MiB
  u16* Wq = (u16*)(ws + (size_t)(24 << 20));  // 2 MiB
  u16* Wo = (u16*)(ws + (size_t)(26 << 20));  // 2 MiB
  u16* qn = (u16*)(ws + (size_t)(28 << 20));  // 8 MiB (normed q-proj, x sc*log2e)
  u16* kn = (u16*)(ws + (size_t)(36 << 20));  // 8 MiB (normed k-proj)
  u16* av = (u16*)(ws + (size_t)(44 << 20));  // 8 MiB (v-proj, then attn out)
  u16* vtb = (u16*)(ws + (size_t)(52 << 20)); // 8 MiB [B,H,64,S]
  u16* bt  = (u16*)(ws + (size_t)(60 << 20)); // 128 MiB [H,T,S] bf16 (x log2e)
  // total 188 MiB

  dim3 blk(256);
  transpose_bias<<<dim3(4, 2048), blk, 0, stream>>>(bias, bt);
  convert_all<<<dim3(2048, 5), blk, 0, stream>>>(q, k, v, Wqkv, Wout,
                                                 qc, kc, vc, Wq, Wo);

  gemm_qkv<<<dim3(8, 32, 3), blk, 0, stream>>>(qc, kc, vc, Wq, ls, qn, kn, av);
  transpose_v<<<dim3(32, 32), blk, 0, stream>>>(av, vtb);
  flash_attn<<<dim3(16, 32), dim3(512), 0, stream>>>(qn, kn, vtb, bt, av);
  gemm_out<<<dim3(8, 32), blk, 0, stream>>>(av, Wo, out);
}

// Round 3
// 647.694 us; speedup vs baseline: 1.0386x; 1.0386x over previous
//
#include <hip/hip_runtime.h>
#include <stdint.h>

typedef unsigned short u16;
using bf16x8 = __attribute__((ext_vector_type(8))) __bf16;
using f32x4  = __attribute__((ext_vector_type(4))) float;
using u16x8  = __attribute__((ext_vector_type(8))) u16;
using u16x4  = __attribute__((ext_vector_type(4))) u16;
using i32x4  = __attribute__((ext_vector_type(4))) int;

#define BB 2
#define TT 2048
#define SQ 2048
#define DM 1024
#define NH 16
#define HD 64
#define LOG2E 1.44269504088896340736f

__device__ __forceinline__ float bf2f(u16 u) {
  uint32_t x = ((uint32_t)u) << 16;
  return __builtin_bit_cast(float, x);
}
__device__ __forceinline__ u16 f2bf(float f) {
  uint32_t x = __builtin_bit_cast(uint32_t, f);
  x += 0x7fffu + ((x >> 16) & 1u);
  return (u16)(x >> 16);
}
__device__ __forceinline__ int cvt_pk_bf16(float lo, float hi) {
  int r;
  asm("v_cvt_pk_bf16_f32 %0, %1, %2" : "=v"(r) : "v"(lo), "v"(hi));
  return r;
}

typedef __attribute__((address_space(1))) void gvoid;
typedef __attribute__((address_space(3))) void lvoid;
__device__ __forceinline__ void g2l16(const void* g, void* l) {
  // async global->LDS, 16B per lane, LDS dest = base + lane*16
  __builtin_amdgcn_global_load_lds((gvoid*)g, (lvoid*)l, 16, 0, 0);
}

// ---------------- fp32 -> bf16 convert (all 5 tensors, one launch) ----------
__global__ __launch_bounds__(256) void convert_all(
    const float* __restrict__ q, const float* __restrict__ k,
    const float* __restrict__ v, const float* __restrict__ wq,
    const float* __restrict__ wo, u16* __restrict__ qc, u16* __restrict__ kc,
    u16* __restrict__ vc, u16* __restrict__ wqc, u16* __restrict__ woc) {
  const float* src;
  u16* dst;
  int n8;
  switch (blockIdx.y) {
    case 0:  src = q;  dst = qc;  n8 = 4096 * 1024 / 8; break;
    case 1:  src = k;  dst = kc;  n8 = 4096 * 1024 / 8; break;
    case 2:  src = v;  dst = vc;  n8 = 4096 * 1024 / 8; break;
    case 3:  src = wq; dst = wqc; n8 = 1024 * 1024 / 8; break;
    default: src = wo; dst = woc; n8 = 1024 * 1024 / 8; break;
  }
  int i = blockIdx.x * 256 + threadIdx.x;
  if (i >= n8) return;
  f32x4 a = ((const f32x4*)src)[(size_t)i * 2];
  f32x4 b = ((const f32x4*)src)[(size_t)i * 2 + 1];
  u16x8 o;
#pragma unroll
  for (int j = 0; j < 4; ++j) { o[j] = f2bf(a[j]); o[4 + j] = f2bf(b[j]); }
  ((u16x8*)dst)[i] = o;
}

// ---------------- GEMM-BT: C[M,1024] = A[M,1024] @ W[1024,1024]^T (bf16) -----
// 128x128 tile, BK=64, fragment-blocked LDS (1KB frags in exact lane order).
// norm_mode: 0 = l2norm rows per 64-col head + logit-scale*log2e (q)
//            1 = l2norm rows per 64-col head (k)
//            2 = plain (v)
template <typename OutT>
__device__ __forceinline__ void gemm_body(const u16* __restrict__ A,
                                          const u16* __restrict__ W,
                                          OutT* __restrict__ C,
                                          const float* __restrict__ ls,
                                          int norm_mode) {
  const int n0 = blockIdx.x * 128;
  const int m0 = blockIdx.y * 128;
  const int tid = threadIdx.x;
  const int w = tid >> 6, lane = tid & 63;
  const int l15 = lane & 15, lg = lane >> 4;
  const int wr = w >> 1, wc = w & 1;

  __shared__ u16 ldsA[16 * 512];
  __shared__ u16 ldsB[16 * 512];

  f32x4 acc[4][4];
#pragma unroll
  for (int i = 0; i < 4; ++i)
#pragma unroll
    for (int j = 0; j < 4; ++j) acc[i][j] = (f32x4){0.f, 0.f, 0.f, 0.f};

  for (int kt = 0; kt < 1024; kt += 64) {
#pragma unroll
    for (int u = 0; u < 4; ++u) {
      int f = w * 4 + u;           // frag id 0..15
      int mt = f >> 1, ks = f & 1; // frag(mt,ks): lane -> [mt*16+l15][ks*32+lg*8]
      g2l16(A + (size_t)(m0 + mt * 16 + l15) * 1024 + kt + ks * 32 + lg * 8,
            &ldsA[f * 512]);
      g2l16(W + (size_t)(n0 + mt * 16 + l15) * 1024 + kt + ks * 32 + lg * 8,
            &ldsB[f * 512]);
    }
    __syncthreads();
#pragma unroll
    for (int ks = 0; ks < 2; ++ks) {
      bf16x8 a[4], b[4];
#pragma unroll
      for (int i = 0; i < 4; ++i)
        a[i] = *(const bf16x8*)&ldsA[((wr * 4 + i) * 2 + ks) * 512 + lane * 8];
#pragma unroll
      for (int j = 0; j < 4; ++j)
        b[j] = *(const bf16x8*)&ldsB[((wc * 4 + j) * 2 + ks) * 512 + lane * 8];
#pragma unroll
      for (int i = 0; i < 4; ++i)
#pragma unroll
        for (int j = 0; j < 4; ++j)
          acc[i][j] = __builtin_amdgcn_mfma_f32_16x16x32_bf16(a[i], b[j],
                                                              acc[i][j], 0, 0, 0);
    }
    __syncthreads();
  }

  // fused per-(row,head) l2norm (+ clamped logit scale for q). Each wave owns
  // one head's 64 cols: col = (wc*4+j)*16+l15 -> head = n0/64 + wc.
  if (norm_mode < 2) {
    float sc = 1.0f;
    if (norm_mode == 0)
      sc = __expf(fminf(ls[(n0 >> 6) + wc], 4.60517019f)) * LOG2E;  // exp2 fold
#pragma unroll
    for (int i = 0; i < 4; ++i)
#pragma unroll
      for (int r = 0; r < 4; ++r) {
        float ss = 0.f;
#pragma unroll
        for (int j = 0; j < 4; ++j) ss += acc[i][j][r] * acc[i][j][r];
#pragma unroll
        for (int d = 1; d < 16; d <<= 1) ss += __shfl_xor(ss, d, 64);
        float f = sc / fmaxf(sqrtf(ss), 1e-12f);
#pragma unroll
        for (int j = 0; j < 4; ++j) acc[i][j][r] *= f;
      }
  }

#pragma unroll
  for (int i = 0; i < 4; ++i) {
    int row0 = m0 + (wr * 4 + i) * 16 + lg * 4;
#pragma unroll
    for (int j = 0; j < 4; ++j) {
      int col = n0 + (wc * 4 + j) * 16 + l15;
#pragma unroll
      for (int r = 0; r < 4; ++r) {
        if constexpr (sizeof(OutT) == 2)
          C[(size_t)(row0 + r) * 1024 + col] = f2bf(acc[i][j][r]);
        else
          C[(size_t)(row0 + r) * 1024 + col] = acc[i][j][r];
      }
    }
  }
}

__global__ __launch_bounds__(256, 2) void gemm_qkv(
    const u16* __restrict__ q, const u16* __restrict__ k,
    const u16* __restrict__ v, const u16* __restrict__ W,
    const float* __restrict__ ls,
    u16* __restrict__ qp, u16* __restrict__ kp, u16* __restrict__ vp) {
  const u16* A;
  u16* C;
  if (blockIdx.z == 0) { A = q; C = qp; }
  else if (blockIdx.z == 1) { A = k; C = kp; }
  else { A = v; C = vp; }
  gemm_body<u16>(A, W, C, ls, blockIdx.z);
}

__global__ __launch_bounds__(256, 2) void gemm_out(const u16* __restrict__ A,
                                                   const u16* __restrict__ W,
                                                   float* __restrict__ C) {
  gemm_body<float>(A, W, C, nullptr, 2);
}

// -------- vt[b][h][d][s] = vp[(b*S+s)*1024 + h*64 + d] --------
__global__ __launch_bounds__(256) void transpose_v(const u16* __restrict__ vp,
                                                   u16* __restrict__ vt) {
  int st = blockIdx.x;           // s-tile (64)
  int bh = blockIdx.y;           // b*16+h
  __shared__ u16 lds[64][72];
  int tid = threadIdx.x;
  int s = tid >> 2, c0 = (tid & 3) * 16;
  int b = bh >> 4, h = bh & 15;
  const u16* src = vp + (size_t)(b * SQ + st * 64 + s) * 1024 + h * 64 + c0;
  u16x8 r0 = *(const u16x8*)src;
  u16x8 r1 = *(const u16x8*)(src + 8);
#pragma unroll
  for (int j = 0; j < 8; ++j) { lds[s][c0 + j] = r0[j]; lds[s][c0 + 8 + j] = r1[j]; }
  __syncthreads();
  int d = tid >> 2, sc = (tid & 3) * 16;
  u16x8 o0, o1;
#pragma unroll
  for (int j = 0; j < 8; ++j) { o0[j] = lds[sc + j][d]; o1[j] = lds[sc + 8 + j][d]; }
  u16* dst = vt + (size_t)(bh * 64 + d) * SQ + st * 64 + sc;
  *(u16x8*)dst = o0;
  *((u16x8*)(dst + 8)) = o1;
}

// -------- bt[h][t][s] (bf16, pre-scaled by log2e) = bias[t][s][h] (fp32) -----
// unit-stride global reads (lane i reads 16B at base + i*16), LDS transpose.
__global__ __launch_bounds__(256) void transpose_bias(const float* __restrict__ bias,
                                                      u16* __restrict__ bt) {
  int t = blockIdx.y;
  int s0 = blockIdx.x * 512;
  __shared__ u16 lds[16][520];
  int tid = threadIdx.x;
  const float* src = bias + ((size_t)t * SQ + s0) * 16;  // block base, 32 KB
  int h0 = (tid & 3) * 4;
  int sr = tid >> 2;  // 0..63
#pragma unroll
  for (int p = 0; p < 8; ++p) {
    // flat float index = p*1024 + tid*4 + e -> s = p*64 + (tid>>2), h = (tid&3)*4+e
    f32x4 r = *(const f32x4*)(src + p * 1024 + tid * 4);
#pragma unroll
    for (int e = 0; e < 4; ++e)
      lds[h0 + e][p * 64 + sr] = f2bf(r[e] * LOG2E);
  }
  __syncthreads();
  int h = tid >> 4, sc = (tid & 15) * 32;
  u16* dst = bt + ((size_t)h * TT + t) * SQ + s0 + sc;
#pragma unroll
  for (int j = 0; j < 4; ++j) {
    u16x8 o;
#pragma unroll
    for (int e = 0; e < 8; ++e) o[e] = lds[h][sc + j * 8 + e];
    *((u16x8*)(dst + j * 8)) = o;
  }
}

// -------- flash attention, KVBLK=64, fixed-max softmax (scores bounded) ------
// v4: occupancy fix. 256-thread blocks (b back in grid), KVBLK=64 so LDS =
// 2buf x (8K K + 8K V) = 32 KB -> 4 blocks/CU co-resident (grid 1024 = 4x256,
// all resident). 4 independent barrier groups per CU cover the vmcnt/barrier
// drain that made v3 latency-bound (Occupancy 22%, MfmaUtil 8%).
// Swapped QK^T (P lane-local), in-register P via cvt_pk + permlane swaps,
// double-buffered staging with counted vmcnt, setprio around MFMA clusters.
// Grid x = b*16+h: same-(b,h) qt-blocks and the b-partner land on the same XCD
// (linear%8 == x%8) -> K/V and bias L2 reuse.
__global__ __launch_bounds__(256, 4) void flash_attn(
    const u16* __restrict__ qn, const u16* __restrict__ kn,
    const u16* __restrict__ vt, const u16* __restrict__ bt,
    u16* __restrict__ av) {
  const int h = blockIdx.x & 15, b = blockIdx.x >> 4, qt = blockIdx.y;
  const int tid = threadIdx.x, w = tid >> 6, lane = tid & 63;
  const int l15 = lane & 15, lg = lane >> 4;

  __shared__ u16 ldsK[2][8 * 512];  // [buf][frag(nt0..3 x ks0..1)]
  __shared__ u16 ldsV[2][8 * 512];  // [buf][frag(j0..3 x ks2 0..1)]

  const int t0 = qt * 64 + w * 16;

  bf16x8 qf[2];
  {
    const u16* qb = qn + (size_t)(b * TT + t0 + l15) * 1024 + h * 64 + lg * 8;
    qf[0] = *(const bf16x8*)qb;
    qf[1] = *(const bf16x8*)(qb + 32);
  }

  f32x4 o[4];
#pragma unroll
  for (int n = 0; n < 4; ++n) o[n] = (f32x4){0.f, 0.f, 0.f, 0.f};
  float li = 0.f;

  const u16* kb = kn + (size_t)(b * SQ) * 1024 + h * 64;
  const u16* vb = vt + (size_t)((b * NH + h) * 64) * SQ;
  // S^T layout: lane needs bias[t = t0+l15][s = st + nt*16 + lg*4 + r]
  const u16* bbl = bt + ((size_t)h * TT + t0 + l15) * SQ + lg * 4;

  // 16 frags/tile (8 K + 8 V), 4 waves x 4 each: waves 0-1 stage K, 2-3 stage V
#define STAGE(bufi, stg)                                                       \
  {                                                                            \
    _Pragma("unroll") for (int u_ = 0; u_ < 4; ++u_) {                         \
      int f_ = w * 4 + u_;                                                     \
      if (f_ < 8) {                                                            \
        int nt_ = f_ >> 1, ks_ = f_ & 1;                                       \
        g2l16(kb + (size_t)((stg) + nt_ * 16 + l15) * 1024 + ks_ * 32 + lg * 8,\
              &ldsK[bufi][f_ * 512]);                                          \
      } else {                                                                 \
        int f2_ = f_ - 8;                                                      \
        int j_ = f2_ >> 1, k2_ = f2_ & 1;                                      \
        g2l16(vb + (size_t)(j_ * 16 + l15) * SQ + (stg) + k2_ * 32 + lg * 8,   \
              &ldsV[bufi][f2_ * 512]);                                         \
      }                                                                        \
    }                                                                          \
  }

  STAGE(0, 0);  // prologue: 4 staging loads in flight per wave

  for (int it = 0; it < 32; ++it) {
    const int cur = it & 1;
    const int st = it * 64;

    // bias tile: 4 x dwordx2, issued BEFORE next-stage so counted waits are
    // exact (per-wave outstanding = cur4 | bias4 | next4).
    u16x4 bv[4];
#pragma unroll
    for (int nt = 0; nt < 4; ++nt)
      bv[nt] = *(const u16x4*)(bbl + st + nt * 16);
    asm volatile("" ::: "memory");  // pin bias loads before staging issue

    if (it < 31) {
      STAGE(cur ^ 1, st + 64);
      // retire cur's 4 staging loads; keep bias(4)+next(4) in flight
      asm volatile("s_waitcnt vmcnt(8)" ::: "memory");
    } else {
      // no next-stage: retire cur's 4, keep bias(4)
      asm volatile("s_waitcnt vmcnt(4)" ::: "memory");
    }
    __builtin_amdgcn_s_barrier();

    // S^T = Kn @ Qn^T: A = K-frag (rows = s), B = Q-frag (cols = t).
    // sacc[nt][r] = S[t = l15][s = st + nt*16 + lg*4 + r]
    f32x4 sacc[4];
    __builtin_amdgcn_s_setprio(1);
#pragma unroll
    for (int nt = 0; nt < 4; ++nt) {
      sacc[nt] = (f32x4){0.f, 0.f, 0.f, 0.f};
#pragma unroll
      for (int ks = 0; ks < 2; ++ks)
        sacc[nt] = __builtin_amdgcn_mfma_f32_16x16x32_bf16(
            *(const bf16x8*)&ldsK[cur][(nt * 2 + ks) * 512 + lane * 8],
            qf[ks], sacc[nt], 0, 0, 0);
    }
    __builtin_amdgcn_s_setprio(0);

    // p = exp2(s + bias); lane-local sum; pack pairs to bf16
    int pk[4][2];
#pragma unroll
    for (int nt = 0; nt < 4; ++nt) {
      float p0 = __builtin_amdgcn_exp2f(sacc[nt][0] + bf2f(bv[nt][0]));
      float p1 = __builtin_amdgcn_exp2f(sacc[nt][1] + bf2f(bv[nt][1]));
      float p2 = __builtin_amdgcn_exp2f(sacc[nt][2] + bf2f(bv[nt][2]));
      float p3 = __builtin_amdgcn_exp2f(sacc[nt][3] + bf2f(bv[nt][3]));
      li += (p0 + p1) + (p2 + p3);
      pk[nt][0] = cvt_pk_bf16(p0, p1);
      pk[nt][1] = cvt_pk_bf16(p2, p3);
    }

    // O += P @ V. Build P A-fragments in-register:
    //   (u,v) = permlane32_swap(A,B)   -> u=[A0,A1,B0,B1], v=[A2,A3,B2,B3]
    //   (u',v') = permlane16_swap(u,v) -> u'=[A0,A2,B0,B2], v'=[A1,A3,B1,B3]
#pragma unroll
    for (int ks2 = 0; ks2 < 2; ++ks2) {
      auto a0 = __builtin_amdgcn_permlane32_swap(pk[2 * ks2][0],
                                                 pk[2 * ks2 + 1][0], false, false);
      auto w0 = __builtin_amdgcn_permlane16_swap(a0[0], a0[1], false, false);
      auto a1 = __builtin_amdgcn_permlane32_swap(pk[2 * ks2][1],
                                                 pk[2 * ks2 + 1][1], false, false);
      auto w1 = __builtin_amdgcn_permlane16_swap(a1[0], a1[1], false, false);
      i32x4 pw = (i32x4){(int)w0[0], (int)w1[0], (int)w0[1], (int)w1[1]};
      bf16x8 pf = __builtin_bit_cast(bf16x8, pw);
      __builtin_amdgcn_s_setprio(1);
#pragma unroll
      for (int j = 0; j < 4; ++j)
        o[j] = __builtin_amdgcn_mfma_f32_16x16x32_bf16(
            pf, *(const bf16x8*)&ldsV[cur][(j * 2 + ks2) * 512 + lane * 8],
            o[j], 0, 0, 0);
      __builtin_amdgcn_s_setprio(0);
    }
    // protect buf[cur] from next iteration's staging overwrite
    if (it < 31) __builtin_amdgcn_s_barrier();
  }
#undef STAGE

  // li holds partial sum for t = l15 over this lane-group's s subset
  li += __shfl_xor(li, 16, 64);
  li += __shfl_xor(li, 32, 64);
  float inv[4];
#pragma unroll
  for (int r = 0; r < 4; ++r) inv[r] = 1.0f / __shfl(li, lg * 4 + r, 64);

#pragma unroll
  for (int j = 0; j < 4; ++j)
#pragma unroll
    for (int r = 0; r < 4; ++r) {
      size_t row = (size_t)(b * TT + t0 + lg * 4 + r);
      av[row * 1024 + h * 64 + j * 16 + l15] = f2bf(o[j][r] * inv[r]);
    }
}

extern "C" void kernel_launch(void* const* d_in, const int* in_sizes, int n_in,
                              void* d_out, int out_size, void* d_ws, size_t ws_size,
                              hipStream_t stream) {
  const float* q    = (const float*)d_in[0];
  const float* k    = (const float*)d_in[1];
  const float* v    = (const float*)d_in[2];
  const float* bias = (const float*)d_in[3];
  const float* Wqkv = (const float*)d_in[4];
  const float* Wout = (const float*)d_in[5];
  const float* ls   = (const float*)d_in[6];
  float* out = (float*)d_out;

  char* ws = (char*)d_ws;
  u16* qc = (u16*)(ws);                       // 8 MiB bf16 [4096,1024]
  u16* kc = (u16*)(ws + (size_t)(8  << 20));  // 8 MiB
  u16* vc = (u16*)(ws + (size_t)(16 << 20));  // 8 MiB
  u16* Wq = (u16*)(ws + (size_t)(24 << 20));  // 2 MiB
  u16* Wo = (u16*)(ws + (size_t)(26 << 20));  // 2 MiB
  u16* qn = (u16*)(ws + (size_t)(28 << 20));  // 8 MiB (normed q-proj, x sc*log2e)
  u16* kn = (u16*)(ws + (size_t)(36 << 20));  // 8 MiB (normed k-proj)
  u16* av = (u16*)(ws + (size_t)(44 << 20));  // 8 MiB (v-proj, then attn out)
  u16* vtb = (u16*)(ws + (size_t)(52 << 20)); // 8 MiB [B,H,64,S]
  u16* bt  = (u16*)(ws + (size_t)(60 << 20)); // 128 MiB [H,T,S] bf16 (x log2e)
  // total 188 MiB

  dim3 blk(256);
  transpose_bias<<<dim3(4, 2048), blk, 0, stream>>>(bias, bt);
  convert_all<<<dim3(2048, 5), blk, 0, stream>>>(q, k, v, Wqkv, Wout,
                                                 qc, kc, vc, Wq, Wo);

  gemm_qkv<<<dim3(8, 32, 3), blk, 0, stream>>>(qc, kc, vc, Wq, ls, qn, kn, av);
  transpose_v<<<dim3(32, 32), blk, 0, stream>>>(av, vtb);
  flash_attn<<<dim3(32, 32), blk, 0, stream>>>(qn, kn, vtb, bt, av);
  gemm_out<<<dim3(8, 32), blk, 0, stream>>>(av, Wo, out);
}